// Round 8
// baseline (61.945 us; speedup 1.0000x reference)
//
#include <hip/hip_runtime.h>

typedef float f32x4 __attribute__((ext_vector_type(4)));

constexpr int B_ = 8, C_ = 128, L_ = 2048;
constexpr int DEG = 12;           // Taylor degree; 13 coefficients m=0..12
constexpr int NM = DEG + 1;
constexpr int TOK = 16;           // tokens per fuse block

__constant__ float c_invfact[NM] = {
    1.0f, 1.0f, 0.5f, 1.0f/6.0f, 1.0f/24.0f, 1.0f/120.0f, 1.0f/720.0f,
    1.0f/5040.0f, 1.0f/40320.0f, 1.0f/362880.0f, 1.0f/3628800.0f,
    1.0f/39916800.0f, 1.0f/479001600.0f};

// ---- Kernel 1: pool rows; last block per batch runs encode+G inline ----
// 1024 blocks (one per (b,c) row) x 256 threads. Row sum -> pooled[row].
// Device-scope atomic counter per batch; the 128th finisher computes
// enc[b][:] = pooled[b]@W.T + bias and G[b][m] = sum_k enc^m/m!.
// Encode work overlaps the pooling of later batches; saves a launch gap.
__global__ __launch_bounds__(256) void pool_encode_kernel(const float* __restrict__ x,
                                                          const float* __restrict__ W,
                                                          const float* __restrict__ bias,
                                                          float* __restrict__ pooled,
                                                          float* __restrict__ enc,
                                                          float* __restrict__ G,
                                                          int* __restrict__ cnt) {
    int row = blockIdx.x;           // b*C + c
    int b   = row >> 7;
    int tid = threadIdx.x;

    // ---- row mean ----
    const float4* xr = (const float4*)(x + (size_t)row * L_);
    float4 a = xr[tid];
    float4 c = xr[tid + 256];
    float s = (a.x + a.y) + (a.z + a.w) + (c.x + c.y) + (c.z + c.w);
    #pragma unroll
    for (int off = 32; off; off >>= 1) s += __shfl_down(s, off, 64);
    __shared__ float wsum[4];
    int lane = tid & 63, wv = tid >> 6;
    if (lane == 0) wsum[wv] = s;
    __syncthreads();

    __shared__ int is_last;
    if (tid == 0) {
        float t = (wsum[0] + wsum[1]) + (wsum[2] + wsum[3]);
        pooled[row] = t * (1.0f / (float)L_);
        __threadfence();            // release pooled[row] before the atomic
        int old = __hip_atomic_fetch_add(&cnt[b], 1, __ATOMIC_ACQ_REL,
                                         __HIP_MEMORY_SCOPE_AGENT);
        is_last = (old == C_ - 1);
    }
    __syncthreads();
    if (!is_last) return;

    // ---- last block of batch b: encode + G ----
    __threadfence();                // acquire side
    __shared__ float p[C_];
    __shared__ float Pl[NM][C_];
    if (tid < C_) p[tid] = ((const volatile float*)pooled)[b * C_ + tid];
    __syncthreads();
    if (tid < C_) {
        float acc = bias[tid];
        const float4* wr = (const float4*)(W + tid * C_);
        #pragma unroll
        for (int j4 = 0; j4 < C_ / 4; ++j4) {
            float4 w4 = wr[j4];
            acc = fmaf(p[4 * j4 + 0], w4.x, acc);
            acc = fmaf(p[4 * j4 + 1], w4.y, acc);
            acc = fmaf(p[4 * j4 + 2], w4.z, acc);
            acc = fmaf(p[4 * j4 + 3], w4.w, acc);
        }
        enc[b * C_ + tid] = acc;
        float t = 1.0f;
        Pl[0][tid] = 1.0f;
        #pragma unroll
        for (int m = 1; m < NM; ++m) {
            t *= acc * (1.0f / (float)m);
            Pl[m][tid] = t;
        }
    }
    __syncthreads();
    for (int s2 = 64; s2 >= 1; s2 >>= 1) {
        if (tid < s2) {
            #pragma unroll
            for (int m = 0; m < NM; ++m) Pl[m][tid] += Pl[m][tid + s2];
        }
        __syncthreads();
    }
    if (tid < NM) G[b * NM + tid] = Pl[tid][0];
}

// ---------------- Kernel 2: polynomial softmax-attention (unchanged) --------
__global__ __launch_bounds__(256) void fuse_kernel(const float* __restrict__ x,
                                                   const float* __restrict__ enc,
                                                   const float* __restrict__ G,
                                                   float* __restrict__ out) {
    int b = blockIdx.x >> 7;            // 0..7
    int l0 = (blockIdx.x & 127) << 4;   // 0..2032 step 16

    __shared__ __align__(16) float fT[TOK][132];    // [tok][k]
    __shared__ __align__(16) float encs[B_][132];   // [eidx][k], padded
    __shared__ __align__(16) float augT[C_ * 20];   // [j][tok]
    __shared__ float Nmom[TOK][14];
    __shared__ float Gs[B_][NM];

    int tid = threadIdx.x;
    const float* xb = x + (size_t)b * (C_ * L_);

    // ---- Phase A ----
    #pragma unroll
    for (int r = 0; r < 2; ++r) {
        int flat = tid + 256 * r;       // 0..511 float4s
        int c4 = flat & 3, k = flat >> 2;
        float4 v = *(const float4*)(xb + k * L_ + l0 + 4 * c4);
        fT[4 * c4 + 0][k] = v.x;
        fT[4 * c4 + 1][k] = v.y;
        fT[4 * c4 + 2][k] = v.z;
        fT[4 * c4 + 3][k] = v.w;
    }
    {   // enc: 8 rows x 128, one float4 per thread into padded rows
        int e = tid >> 5, c4 = tid & 31;
        *(f32x4*)&encs[e][4 * c4] = *(const f32x4*)(enc + e * C_ + 4 * c4);
    }
    if (tid < B_ * NM) ((float*)Gs)[tid] = G[tid];
    __syncthreads();

    // ---- Phase B: moments (in-register power recurrence) ----
    {
        int tok = tid >> 4;             // 0..15
        int g   = tid & 15;             // 0..15
        int eidx = tok & 7;             // (b*L + l0 + tok) % 8 == tok % 8
        f32x4 fa = *(const f32x4*)&fT[tok][8 * g];
        f32x4 fb = *(const f32x4*)&fT[tok][8 * g + 4];
        f32x4 ea = *(const f32x4*)&encs[eidx][8 * g];
        f32x4 eb = *(const f32x4*)&encs[eidx][8 * g + 4];
        float part[NM];
        part[0] = ((fa.x + fa.y) + (fa.z + fa.w)) + ((fb.x + fb.y) + (fb.z + fb.w));
        f32x4 pa = ea, pb = eb;         // e^1
        #pragma unroll
        for (int m = 1; m < NM; ++m) {
            if (m > 1) { pa *= ea; pb *= eb; }   // e^m raw; scaled at writeback
            float d = pa.x * fa.x;
            d = fmaf(pa.y, fa.y, d); d = fmaf(pa.z, fa.z, d); d = fmaf(pa.w, fa.w, d);
            d = fmaf(pb.x, fb.x, d); d = fmaf(pb.y, fb.y, d);
            d = fmaf(pb.z, fb.z, d); d = fmaf(pb.w, fb.w, d);
            part[m] = d;
        }
        #pragma unroll
        for (int mask = 1; mask <= 8; mask <<= 1) {
            #pragma unroll
            for (int m = 0; m < NM; ++m) part[m] += __shfl_xor(part[m], mask, 64);
        }
        if (g == 0) {
            #pragma unroll
            for (int m = 0; m < NM; ++m) Nmom[tok][m] = part[m] * c_invfact[m];
        }
    }
    __syncthreads();

    // ---- Phase C: Horner + rcp -> augT ----
    {
        int q     = tid & 7;            // token low bits (== eidx)
        int jbase = (tid >> 3) & 31;
        float Gt[NM], N0[NM], N1[NM];
        #pragma unroll
        for (int m = 0; m < NM; ++m) {
            Gt[m] = Gs[q][m];
            N0[m] = Nmom[q][m];
            N1[m] = Nmom[q + 8][m];
        }
        #pragma unroll
        for (int ji = 0; ji < 4; ++ji) {
            int j = jbase + 32 * ji;
            float s0 = fT[q][j];
            float s1 = fT[q + 8][j];
            float h0 = N0[DEG], g0 = Gt[DEG];
            float h1 = N1[DEG], g1 = Gt[DEG];
            #pragma unroll
            for (int m = DEG - 1; m >= 0; --m) {
                h0 = fmaf(h0, s0, N0[m]);
                g0 = fmaf(g0, s0, Gt[m]);
                h1 = fmaf(h1, s1, N1[m]);
                g1 = fmaf(g1, s1, Gt[m]);
            }
            augT[j * 20 + q]     = h0 * __builtin_amdgcn_rcpf(g0);
            augT[j * 20 + q + 8] = h1 * __builtin_amdgcn_rcpf(g1);
        }
    }
    __syncthreads();

    // ---- Coalesced float4 stores (full 64B lines) ----
    float* ob = out + (size_t)b * (C_ * L_) + l0;
    #pragma unroll
    for (int r = 0; r < 2; ++r) {
        int flat = tid + 256 * r;       // 0..511 float4s
        int c4 = flat & 3, j = flat >> 2;
        float4 v = *(const float4*)&augT[j * 20 + 4 * c4];
        *(float4*)(ob + j * L_ + 4 * c4) = v;
    }
}

extern "C" void kernel_launch(void* const* d_in, const int* in_sizes, int n_in,
                              void* d_out, int out_size, void* d_ws, size_t ws_size,
                              hipStream_t stream) {
    const float* x    = (const float*)d_in[0];
    const float* W    = (const float*)d_in[1];
    const float* bias = (const float*)d_in[2];
    float* out = (float*)d_out;

    float* pooled = (float*)d_ws;            // 1024 f32
    float* enc    = pooled + 1024;           // 1024 f32
    float* G      = enc + B_ * C_;           // 104 f32
    int*   cnt    = (int*)(G + B_ * NM);     // 8 ints

    hipMemsetAsync(cnt, 0, B_ * sizeof(int), stream);   // graph-legal reset
    pool_encode_kernel<<<B_ * C_, 256, 0, stream>>>(x, W, bias, pooled, enc, G, cnt);
    fuse_kernel<<<B_ * (L_ / TOK), 256, 0, stream>>>(x, enc, G, out);
}

// Round 9
// 36.257 us; speedup vs baseline: 1.7085x; 1.7085x over previous
//
#include <hip/hip_runtime.h>

typedef float f32x4 __attribute__((ext_vector_type(4)));

constexpr int B_ = 8, C_ = 128, L_ = 2048;
constexpr int DEG = 12;           // Taylor degree; 13 coefficients m=0..12
constexpr int NM = DEG + 1;
constexpr int TOK = 16;           // tokens per fuse block

__constant__ float c_invfact[NM] = {
    1.0f, 1.0f, 0.5f, 1.0f/6.0f, 1.0f/24.0f, 1.0f/120.0f, 1.0f/720.0f,
    1.0f/5040.0f, 1.0f/40320.0f, 1.0f/362880.0f, 1.0f/3628800.0f,
    1.0f/39916800.0f, 1.0f/479001600.0f};

// 16-lane DPP all-reduce stage: add value from a lane permutation (VALU-only,
// no LDS pipe). 0xB1=quad_perm(1,0,3,2) [xor1], 0x4E=quad_perm(2,3,0,1) [xor2],
// 0x141=row_half_mirror [xor-other-quad], 0x140=row_mirror [other 8].
template<int CTRL>
__device__ __forceinline__ float dppadd(float v) {
    int m = __builtin_amdgcn_update_dpp(0, __float_as_int(v), CTRL, 0xF, 0xF, true);
    return v + __int_as_float(m);
}

// ---- Kernel 1: pool rows; last block per batch runs encode+G inline.
// RELAXED device-scope atomics only — no fences (R8 showed agent fences cost
// ~47us grid-wide via L2 writeback/invalidate storms).
__global__ __launch_bounds__(256) void pool_encode_kernel(const float* __restrict__ x,
                                                          const float* __restrict__ W,
                                                          const float* __restrict__ bias,
                                                          float* __restrict__ pooled,
                                                          float* __restrict__ enc,
                                                          float* __restrict__ G,
                                                          int* __restrict__ cnt) {
    int row = blockIdx.x;           // b*C + c
    int b   = row >> 7;
    int tid = threadIdx.x;

    // ---- row mean ----
    const float4* xr = (const float4*)(x + (size_t)row * L_);
    float4 a = xr[tid];
    float4 c = xr[tid + 256];
    float s = (a.x + a.y) + (a.z + a.w) + (c.x + c.y) + (c.z + c.w);
    #pragma unroll
    for (int off = 32; off; off >>= 1) s += __shfl_down(s, off, 64);
    __shared__ float wsum[4];
    int lane = tid & 63, wv = tid >> 6;
    if (lane == 0) wsum[wv] = s;
    __syncthreads();

    __shared__ int is_last;
    if (tid == 0) {
        float t = (wsum[0] + wsum[1]) + (wsum[2] + wsum[3]);
        // coherence-point store (no cache maintenance)
        __hip_atomic_store(&pooled[row], t * (1.0f / (float)L_),
                           __ATOMIC_RELAXED, __HIP_MEMORY_SCOPE_AGENT);
        // order the store before the counter bump (same-wave vmem ordering)
        asm volatile("s_waitcnt vmcnt(0)" ::: "memory");
        int old = __hip_atomic_fetch_add(&cnt[b], 1, __ATOMIC_RELAXED,
                                         __HIP_MEMORY_SCOPE_AGENT);
        is_last = (old == C_ - 1);
    }
    __syncthreads();
    if (!is_last) return;

    // ---- last block of batch b: encode + G ----
    __shared__ float p[C_];
    __shared__ float Pl[NM][C_];
    if (tid < C_)
        p[tid] = __hip_atomic_load(&pooled[b * C_ + tid],
                                   __ATOMIC_RELAXED, __HIP_MEMORY_SCOPE_AGENT);
    __syncthreads();
    if (tid < C_) {
        // 4 accumulators: break the 128-long fma dependency chain
        float a0 = bias[tid], a1 = 0.f, a2 = 0.f, a3 = 0.f;
        const float4* wr = (const float4*)(W + tid * C_);
        #pragma unroll
        for (int i = 0; i < 8; ++i) {
            float4 w0 = wr[4 * i + 0], w1 = wr[4 * i + 1];
            float4 w2 = wr[4 * i + 2], w3 = wr[4 * i + 3];
            a0 = fmaf(p[16 * i + 0], w0.x, a0); a0 = fmaf(p[16 * i + 1], w0.y, a0);
            a0 = fmaf(p[16 * i + 2], w0.z, a0); a0 = fmaf(p[16 * i + 3], w0.w, a0);
            a1 = fmaf(p[16 * i + 4], w1.x, a1); a1 = fmaf(p[16 * i + 5], w1.y, a1);
            a1 = fmaf(p[16 * i + 6], w1.z, a1); a1 = fmaf(p[16 * i + 7], w1.w, a1);
            a2 = fmaf(p[16 * i + 8], w2.x, a2); a2 = fmaf(p[16 * i + 9], w2.y, a2);
            a2 = fmaf(p[16 * i +10], w2.z, a2); a2 = fmaf(p[16 * i +11], w2.w, a2);
            a3 = fmaf(p[16 * i +12], w3.x, a3); a3 = fmaf(p[16 * i +13], w3.y, a3);
            a3 = fmaf(p[16 * i +14], w3.z, a3); a3 = fmaf(p[16 * i +15], w3.w, a3);
        }
        float acc = (a0 + a1) + (a2 + a3);
        enc[b * C_ + tid] = acc;
        float t = 1.0f;
        Pl[0][tid] = 1.0f;
        #pragma unroll
        for (int m = 1; m < NM; ++m) {
            t *= acc * (1.0f / (float)m);
            Pl[m][tid] = t;
        }
    }
    __syncthreads();
    for (int s2 = 64; s2 >= 1; s2 >>= 1) {
        if (tid < s2) {
            #pragma unroll
            for (int m = 0; m < NM; ++m) Pl[m][tid] += Pl[m][tid + s2];
        }
        __syncthreads();
    }
    if (tid < NM) G[b * NM + tid] = Pl[tid][0];
}

// ---------------- Kernel 2: polynomial softmax-attention ----------------
// 1024 blocks x 256 threads; 16 tokens/block. Thread = (tok = tid>>4, g = tid&15).
// Phase B: 13 moments over lane-local 8 k's, 16-lane DPP all-reduce (VALU only).
// Phase C: same lanes, moments stay in registers; j = g + 16*ji outputs.
__global__ __launch_bounds__(256) void fuse_kernel(const float* __restrict__ x,
                                                   const float* __restrict__ enc,
                                                   const float* __restrict__ G,
                                                   float* __restrict__ out) {
    int b = blockIdx.x >> 7;            // 0..7
    int l0 = (blockIdx.x & 127) << 4;   // 0..2032 step 16

    __shared__ __align__(16) float fT[TOK][132];    // [tok][k]
    __shared__ __align__(16) float encs[B_][132];   // [eidx][k], padded
    __shared__ __align__(16) float augT[C_ * 20];   // [j][tok]
    __shared__ float Gs[B_][NM];

    int tid = threadIdx.x;
    const float* xb = x + (size_t)b * (C_ * L_);

    // ---- Phase A: stage x slice, enc table, G ----
    #pragma unroll
    for (int r = 0; r < 2; ++r) {
        int flat = tid + 256 * r;       // 0..511 float4s
        int c4 = flat & 3, k = flat >> 2;
        float4 v = *(const float4*)(xb + k * L_ + l0 + 4 * c4);
        fT[4 * c4 + 0][k] = v.x;
        fT[4 * c4 + 1][k] = v.y;
        fT[4 * c4 + 2][k] = v.z;
        fT[4 * c4 + 3][k] = v.w;
    }
    {   // enc: 8 rows x 128, one float4 per thread into padded rows
        int e = tid >> 5, c4 = tid & 31;
        *(f32x4*)&encs[e][4 * c4] = *(const f32x4*)(enc + e * C_ + 4 * c4);
    }
    if (tid < B_ * NM) ((float*)Gs)[tid] = G[tid];
    __syncthreads();

    int tok  = tid >> 4;                // 0..15
    int g    = tid & 15;                // 0..15
    int eidx = tok & 7;                 // (b*L + l0 + tok) % 8 == tok % 8

    // ---- Phase B: moments, in-register powers, DPP 16-lane all-reduce ----
    f32x4 fa = *(const f32x4*)&fT[tok][8 * g];
    f32x4 fb = *(const f32x4*)&fT[tok][8 * g + 4];
    f32x4 ea = *(const f32x4*)&encs[eidx][8 * g];
    f32x4 eb = *(const f32x4*)&encs[eidx][8 * g + 4];
    float part[NM];
    part[0] = ((fa.x + fa.y) + (fa.z + fa.w)) + ((fb.x + fb.y) + (fb.z + fb.w));
    f32x4 pa = ea, pb = eb;             // e^1
    #pragma unroll
    for (int m = 1; m < NM; ++m) {
        if (m > 1) { pa *= ea; pb *= eb; }   // e^m raw; 1/m! applied below
        float d = pa.x * fa.x;
        d = fmaf(pa.y, fa.y, d); d = fmaf(pa.z, fa.z, d); d = fmaf(pa.w, fa.w, d);
        d = fmaf(pb.x, fb.x, d); d = fmaf(pb.y, fb.y, d);
        d = fmaf(pb.z, fb.z, d); d = fmaf(pb.w, fb.w, d);
        part[m] = d;
    }
    #pragma unroll
    for (int m = 0; m < NM; ++m) {
        float v = part[m];
        v = dppadd<0xB1>(v);            // xor1 (quad_perm 1,0,3,2)
        v = dppadd<0x4E>(v);            // xor2 (quad_perm 2,3,0,1)
        v = dppadd<0x141>(v);           // other quad (row_half_mirror)
        v = dppadd<0x140>(v);           // other 8 (row_mirror)
        part[m] = v * c_invfact[m];     // all 16 lanes hold N_m[tok]
    }

    // ---- Phase C: Horner + rcp -> augT (no barrier needed: regs carry N) ----
    float Gt[NM];
    #pragma unroll
    for (int m = 0; m < NM; ++m) Gt[m] = Gs[eidx][m];
    #pragma unroll
    for (int ji = 0; ji < 8; ++ji) {
        int j = g + 16 * ji;
        float sv = fT[tok][j];
        float h = part[DEG], gd = Gt[DEG];
        #pragma unroll
        for (int m = DEG - 1; m >= 0; --m) {
            h  = fmaf(h,  sv, part[m]);
            gd = fmaf(gd, sv, Gt[m]);
        }
        augT[j * 20 + tok] = h * __builtin_amdgcn_rcpf(gd);
    }
    __syncthreads();

    // ---- Coalesced float4 stores (full 64B lines) ----
    float* ob = out + (size_t)b * (C_ * L_) + l0;
    #pragma unroll
    for (int r = 0; r < 2; ++r) {
        int flat = tid + 256 * r;       // 0..511 float4s
        int c4 = flat & 3, j = flat >> 2;
        float4 v = *(const float4*)&augT[j * 20 + 4 * c4];
        *(float4*)(ob + j * L_ + 4 * c4) = v;
    }
}

extern "C" void kernel_launch(void* const* d_in, const int* in_sizes, int n_in,
                              void* d_out, int out_size, void* d_ws, size_t ws_size,
                              hipStream_t stream) {
    const float* x    = (const float*)d_in[0];
    const float* W    = (const float*)d_in[1];
    const float* bias = (const float*)d_in[2];
    float* out = (float*)d_out;

    float* pooled = (float*)d_ws;            // 1024 f32
    float* enc    = pooled + 1024;           // 1024 f32
    float* G      = enc + B_ * C_;           // 104 f32
    int*   cnt    = (int*)(G + B_ * NM);     // 8 ints

    hipMemsetAsync(cnt, 0, B_ * sizeof(int), stream);   // graph-legal reset
    pool_encode_kernel<<<B_ * C_, 256, 0, stream>>>(x, W, bias, pooled, enc, G, cnt);
    fuse_kernel<<<B_ * (L_ / TOK), 256, 0, stream>>>(x, enc, G, out);
}

// Round 10
// 18.534 us; speedup vs baseline: 3.3422x; 1.9562x over previous
//
#include <hip/hip_runtime.h>

typedef float f32x4 __attribute__((ext_vector_type(4)));

constexpr int B_ = 8, C_ = 128, L_ = 2048;
constexpr int DEG = 12;           // Taylor degree; 13 coefficients m=0..12
constexpr int NM = DEG + 1;
constexpr int TOK = 16;           // tokens per fuse block
constexpr int CNT_STRIDE = 32;    // ints; one counter per 128-B line

__constant__ float c_invfact[NM] = {
    1.0f, 1.0f, 0.5f, 1.0f/6.0f, 1.0f/24.0f, 1.0f/120.0f, 1.0f/720.0f,
    1.0f/5040.0f, 1.0f/40320.0f, 1.0f/362880.0f, 1.0f/3628800.0f,
    1.0f/39916800.0f, 1.0f/479001600.0f};

// 16-lane DPP all-reduce stage (VALU-only).
template<int CTRL>
__device__ __forceinline__ float dppadd(float v) {
    int m = __builtin_amdgcn_update_dpp(0, __float_as_int(v), CTRL, 0xF, 0xF, true);
    return v + __int_as_float(m);
}

// ---- Kernel 1: pool (8 rows/block, 128 blocks); winner block per batch
// runs encode+G inline. Low-contention: one padded counter per batch,
// depth 16; winner test (old&15)==15 is start-value-agnostic -> no reset
// node needed. Relaxed agent atomics only, no fences (R8 lesson).
__global__ __launch_bounds__(256) void pool_encode_kernel(const float* __restrict__ x,
                                                          const float* __restrict__ W,
                                                          const float* __restrict__ bias,
                                                          float* __restrict__ pooled,
                                                          float* __restrict__ enc,
                                                          float* __restrict__ G,
                                                          int* __restrict__ cnt) {
    int tid  = threadIdx.x;
    int rg   = tid >> 5;            // 0..7 row within block
    int lane = tid & 31;
    int row  = (blockIdx.x << 3) + rg;      // 0..1023 = b*C + c
    int b    = blockIdx.x >> 4;             // 16 blocks per batch

    // ---- row mean: 32 lanes x 16 float4 per row ----
    const float4* xr = (const float4*)(x + (size_t)row * L_);
    float4 a0 = {0,0,0,0};
    #pragma unroll
    for (int i = 0; i < 16; ++i) {
        float4 v = xr[lane + 32 * i];
        a0.x += v.x; a0.y += v.y; a0.z += v.z; a0.w += v.w;
    }
    float s = (a0.x + a0.y) + (a0.z + a0.w);
    #pragma unroll
    for (int m = 1; m <= 16; m <<= 1) s += __shfl_xor(s, m, 32);
    if (lane == 0)
        __hip_atomic_store(&pooled[row], s * (1.0f / (float)L_),
                           __ATOMIC_RELAXED, __HIP_MEMORY_SCOPE_AGENT);
    __syncthreads();                // drains vmem stores before barrier

    __shared__ int is_last;
    if (tid == 0) {
        int old = __hip_atomic_fetch_add(&cnt[b * CNT_STRIDE], 1,
                                         __ATOMIC_RELAXED, __HIP_MEMORY_SCOPE_AGENT);
        is_last = ((old & 15) == 15);
    }
    __syncthreads();
    if (!is_last) return;

    // ---- winner: encode + G for batch b ----
    __shared__ float p[C_];
    __shared__ float Pl[NM][C_];
    if (tid < C_)
        p[tid] = __hip_atomic_load(&pooled[b * C_ + tid],
                                   __ATOMIC_RELAXED, __HIP_MEMORY_SCOPE_AGENT);
    __syncthreads();
    if (tid < C_) {
        float a0_ = bias[tid], a1 = 0.f, a2 = 0.f, a3 = 0.f;
        const float4* wr = (const float4*)(W + tid * C_);
        #pragma unroll
        for (int i = 0; i < 8; ++i) {
            float4 w0 = wr[4 * i + 0], w1 = wr[4 * i + 1];
            float4 w2 = wr[4 * i + 2], w3 = wr[4 * i + 3];
            a0_ = fmaf(p[16 * i + 0], w0.x, a0_); a0_ = fmaf(p[16 * i + 1], w0.y, a0_);
            a0_ = fmaf(p[16 * i + 2], w0.z, a0_); a0_ = fmaf(p[16 * i + 3], w0.w, a0_);
            a1 = fmaf(p[16 * i + 4], w1.x, a1); a1 = fmaf(p[16 * i + 5], w1.y, a1);
            a1 = fmaf(p[16 * i + 6], w1.z, a1); a1 = fmaf(p[16 * i + 7], w1.w, a1);
            a2 = fmaf(p[16 * i + 8], w2.x, a2); a2 = fmaf(p[16 * i + 9], w2.y, a2);
            a2 = fmaf(p[16 * i +10], w2.z, a2); a2 = fmaf(p[16 * i +11], w2.w, a2);
            a3 = fmaf(p[16 * i +12], w3.x, a3); a3 = fmaf(p[16 * i +13], w3.y, a3);
            a3 = fmaf(p[16 * i +14], w3.z, a3); a3 = fmaf(p[16 * i +15], w3.w, a3);
        }
        float acc = (a0_ + a1) + (a2 + a3);
        enc[b * C_ + tid] = acc;
        float t = 1.0f;
        Pl[0][tid] = 1.0f;
        #pragma unroll
        for (int m = 1; m < NM; ++m) {
            t *= acc * (1.0f / (float)m);
            Pl[m][tid] = t;
        }
    }
    __syncthreads();
    for (int s2 = 64; s2 >= 1; s2 >>= 1) {
        if (tid < s2) {
            #pragma unroll
            for (int m = 0; m < NM; ++m) Pl[m][tid] += Pl[m][tid + s2];
        }
        __syncthreads();
    }
    if (tid < NM) G[b * NM + tid] = Pl[tid][0];
}

// ---------------- Kernel 2: polynomial softmax-attention (R9 DPP) ----------
__global__ __launch_bounds__(256) void fuse_kernel(const float* __restrict__ x,
                                                   const float* __restrict__ enc,
                                                   const float* __restrict__ G,
                                                   float* __restrict__ out) {
    int b = blockIdx.x >> 7;            // 0..7
    int l0 = (blockIdx.x & 127) << 4;   // 0..2032 step 16

    __shared__ __align__(16) float fT[TOK][132];    // [tok][k]
    __shared__ __align__(16) float encs[B_][132];   // [eidx][k], padded
    __shared__ __align__(16) float augT[C_ * 20];   // [j][tok]
    __shared__ float Gs[B_][NM];

    int tid = threadIdx.x;
    const float* xb = x + (size_t)b * (C_ * L_);

    // ---- Phase A: stage x slice, enc table, G ----
    #pragma unroll
    for (int r = 0; r < 2; ++r) {
        int flat = tid + 256 * r;       // 0..511 float4s
        int c4 = flat & 3, k = flat >> 2;
        float4 v = *(const float4*)(xb + k * L_ + l0 + 4 * c4);
        fT[4 * c4 + 0][k] = v.x;
        fT[4 * c4 + 1][k] = v.y;
        fT[4 * c4 + 2][k] = v.z;
        fT[4 * c4 + 3][k] = v.w;
    }
    {   // enc: 8 rows x 128, one float4 per thread into padded rows
        int e = tid >> 5, c4 = tid & 31;
        *(f32x4*)&encs[e][4 * c4] = *(const f32x4*)(enc + e * C_ + 4 * c4);
    }
    if (tid < B_ * NM) ((float*)Gs)[tid] = G[tid];
    __syncthreads();

    int tok  = tid >> 4;                // 0..15
    int g    = tid & 15;                // 0..15
    int eidx = tok & 7;                 // (b*L + l0 + tok) % 8 == tok % 8

    // ---- Phase B: moments, in-register powers, DPP 16-lane all-reduce ----
    f32x4 fa = *(const f32x4*)&fT[tok][8 * g];
    f32x4 fb = *(const f32x4*)&fT[tok][8 * g + 4];
    f32x4 ea = *(const f32x4*)&encs[eidx][8 * g];
    f32x4 eb = *(const f32x4*)&encs[eidx][8 * g + 4];
    float part[NM];
    part[0] = ((fa.x + fa.y) + (fa.z + fa.w)) + ((fb.x + fb.y) + (fb.z + fb.w));
    f32x4 pa = ea, pb = eb;             // e^1
    #pragma unroll
    for (int m = 1; m < NM; ++m) {
        if (m > 1) { pa *= ea; pb *= eb; }   // e^m raw; 1/m! applied below
        float d = pa.x * fa.x;
        d = fmaf(pa.y, fa.y, d); d = fmaf(pa.z, fa.z, d); d = fmaf(pa.w, fa.w, d);
        d = fmaf(pb.x, fb.x, d); d = fmaf(pb.y, fb.y, d);
        d = fmaf(pb.z, fb.z, d); d = fmaf(pb.w, fb.w, d);
        part[m] = d;
    }
    #pragma unroll
    for (int m = 0; m < NM; ++m) {
        float v = part[m];
        v = dppadd<0xB1>(v);            // xor1
        v = dppadd<0x4E>(v);            // xor2
        v = dppadd<0x141>(v);           // row_half_mirror (xor4)
        v = dppadd<0x140>(v);           // row_mirror (xor8)
        part[m] = v * c_invfact[m];     // all 16 lanes hold N_m[tok]
    }

    // ---- Phase C: Horner + rcp -> augT ----
    float Gt[NM];
    #pragma unroll
    for (int m = 0; m < NM; ++m) Gt[m] = Gs[eidx][m];
    #pragma unroll
    for (int ji = 0; ji < 8; ++ji) {
        int j = g + 16 * ji;
        float sv = fT[tok][j];
        float h = part[DEG], gd = Gt[DEG];
        #pragma unroll
        for (int m = DEG - 1; m >= 0; --m) {
            h  = fmaf(h,  sv, part[m]);
            gd = fmaf(gd, sv, Gt[m]);
        }
        augT[j * 20 + tok] = h * __builtin_amdgcn_rcpf(gd);
    }
    __syncthreads();

    // ---- Coalesced float4 stores (full 64B lines) ----
    float* ob = out + (size_t)b * (C_ * L_) + l0;
    #pragma unroll
    for (int r = 0; r < 2; ++r) {
        int flat = tid + 256 * r;       // 0..511 float4s
        int c4 = flat & 3, j = flat >> 2;
        float4 v = *(const float4*)&augT[j * 20 + 4 * c4];
        *(float4*)(ob + j * L_ + 4 * c4) = v;
    }
}

extern "C" void kernel_launch(void* const* d_in, const int* in_sizes, int n_in,
                              void* d_out, int out_size, void* d_ws, size_t ws_size,
                              hipStream_t stream) {
    const float* x    = (const float*)d_in[0];
    const float* W    = (const float*)d_in[1];
    const float* bias = (const float*)d_in[2];
    float* out = (float*)d_out;

    float* pooled = (float*)d_ws;            // 1024 f32
    float* enc    = pooled + 1024;           // 1024 f32
    float* G      = enc + B_ * C_;           // 104 f32
    int*   cnt    = (int*)(G + B_ * NM);     // 8 counters, 128-B apart

    pool_encode_kernel<<<C_ * B_ / 8, 256, 0, stream>>>(x, W, bias, pooled, enc, G, cnt);
    fuse_kernel<<<B_ * (L_ / TOK), 256, 0, stream>>>(x, enc, G, out);
}